// Round 1
// baseline (108.812 us; speedup 1.0000x reference)
//
#include <hip/hip_runtime.h>
#include <math.h>

#define NPARAMS 30
#define NX 13

__global__ __launch_bounds__(256) void t1d_kernel(
    const float* __restrict__ x,
    const float* __restrict__ params,
    const float* __restrict__ CHO,
    const float* __restrict__ insulin_u,
    const float* __restrict__ last_Qsto,
    const float* __restrict__ last_foodtaken,
    float* __restrict__ out,
    int n)
{
    int i = blockIdx.x * blockDim.x + threadIdx.x;
    if (i >= n) return;

    const float* p = params + (size_t)i * NPARAMS;
    float kmax = p[0],  kmin = p[1],  b    = p[2],  d_   = p[3];
    float kabs = p[4],  f    = p[5],  BW   = p[6],  kp1  = p[7];
    float kp2  = p[8],  kp3  = p[9],  Fsnc = p[10], ke1  = p[11];
    float ke2  = p[12], k1   = p[13], k2   = p[14], Vm0  = p[15];
    float Vmx  = p[16], Km0  = p[17], m1   = p[18], m2   = p[19];
    float m4   = p[20], m30  = p[21], ka1  = p[22], ka2  = p[23];
    float kd   = p[24], Vi   = p[25], p2u  = p[26], Ib   = p[27];
    float ki   = p[28], ksc  = p[29];

    const float* xr = x + (size_t)i * NX;
    float x0 = xr[0], x1 = xr[1], x2 = xr[2], x3 = xr[3], x4 = xr[4];
    float x5 = xr[5], x6 = xr[6], x7 = xr[7], x8 = xr[8], x9 = xr[9];
    float x10 = xr[10], x11 = xr[11], x12 = xr[12];

    float d       = CHO[i] * 1000.0f;
    float insulin = insulin_u[i] * 6000.0f / BW;

    float qsto = x0 + x1;
    float Dbar = last_Qsto[i] + last_foodtaken[i];
    bool has_food = Dbar > 0.0f;
    float Dbar_safe = has_food ? Dbar : 1.0f;
    float aa = 2.5f / (1.0f - b) / Dbar_safe;
    float cc = 2.5f / d_ / Dbar_safe;
    float kgut_eating = kmin + (kmax - kmin) * 0.5f *
        (tanhf(aa * (qsto - b * Dbar)) - tanhf(cc * (qsto - d_ * Dbar)) + 2.0f);
    float kgut = has_food ? kgut_eating : kmax;

    float d0 = -kmax * x0 + d;
    float d1 = kmax * x0 - x1 * kgut;
    float d2 = kgut * x1 - kabs * x2;

    float Rat  = f * kabs * x2 / BW;
    float EGPt = kp1 - kp2 * x3 - kp3 * x8;
    float Uiit = Fsnc;
    float Et   = (x3 > ke2) ? ke1 * (x3 - ke2) : 0.0f;
    float d3 = (fmaxf(EGPt, 0.0f) + Rat - Uiit - Et - k1 * x3 + k2 * x4) *
               (x3 >= 0.0f ? 1.0f : 0.0f);

    float Vmt  = Vm0 + Vmx * x6;
    float Uidt = Vmt * x4 / (Km0 + x4);
    float d4 = (-Uidt + k1 * x3 - k2 * x4) * (x4 >= 0.0f ? 1.0f : 0.0f);

    float d5 = (-(m2 + m4) * x5 + m1 * x9 + ka1 * x10 + ka2 * x11) *
               (x5 >= 0.0f ? 1.0f : 0.0f);
    float It = x5 / Vi;
    float d6 = -p2u * x6 + p2u * (It - Ib);
    float d7 = -ki * (x7 - It);
    float d8 = -ki * (x8 - x7);
    float d9  = (-(m1 + m30) * x9 + m2 * x5) * (x9 >= 0.0f ? 1.0f : 0.0f);
    float d10 = (insulin - (ka1 + kd) * x10) * (x10 >= 0.0f ? 1.0f : 0.0f);
    float d11 = (kd * x10 - ka2 * x11) * (x11 >= 0.0f ? 1.0f : 0.0f);
    float d12 = (-ksc * x12 + ksc * x3) * (x12 >= 0.0f ? 1.0f : 0.0f);

    float* o = out + (size_t)i * NX;
    o[0] = d0;  o[1] = d1;  o[2] = d2;  o[3] = d3;  o[4] = d4;
    o[5] = d5;  o[6] = d6;  o[7] = d7;  o[8] = d8;  o[9] = d9;
    o[10] = d10; o[11] = d11; o[12] = d12;
}

extern "C" void kernel_launch(void* const* d_in, const int* in_sizes, int n_in,
                              void* d_out, int out_size, void* d_ws, size_t ws_size,
                              hipStream_t stream) {
    const float* x    = (const float*)d_in[0];
    const float* par  = (const float*)d_in[1];
    const float* CHO  = (const float*)d_in[2];
    const float* ins  = (const float*)d_in[3];
    const float* lq   = (const float*)d_in[4];
    const float* lf   = (const float*)d_in[5];
    float* out = (float*)d_out;
    int n = in_sizes[2];  // B (CHO length)

    int block = 256;
    int grid = (n + block - 1) / block;
    t1d_kernel<<<grid, block, 0, stream>>>(x, par, CHO, ins, lq, lf, out, n);
}